// Round 8
// baseline (493.266 us; speedup 1.0000x reference)
//
#include <hip/hip_runtime.h>
#include <hip/hip_bf16.h>

// SineLayer: y[b,o] = sum_{i,d} sin(w_d*x[b,i]+p_d) * (scale_d*c[o,i,d]) + offs[o]
// GEMM: M=32768, N=512, K=4096, bf16 MFMA 16x16x32.
// R8: B never touches LDS. cb stored in MFMA-fragment layout (1KB frag =
// one wave-coalesced global_load_dwordx4 per lane group); B-frags register-
// double-buffered (bfrA/bfrB) with loads in flight across the barrier.
// LDS holds only A (sins): traffic 272->80 KB/kt. Barrier drains lgkm only.

#define BATCH 32768
#define NIN   256
#define NOUT  512
#define DDIM  16
#define BM    128
#define BN    512
#define BK    64
#define NKT   ((NIN*DDIM)/BK)     // 64 K-steps
#define ABYTES (BM*BK*2)          // 16 KB per A buffer
#define EPSV  1e-8f
#define INV2PI 0.15915494309189535f

typedef short  bf16x8 __attribute__((ext_vector_type(8)));
typedef float  f32x4  __attribute__((ext_vector_type(4)));

static __device__ __forceinline__ ushort f2bf(float f) {
  union { __hip_bfloat16 h; ushort u; } cv;
  cv.h = __float2bfloat16(f);
  return cv.u;
}

static __device__ __forceinline__ float sgpr_f(float v) {
  return __builtin_bit_cast(float,
      __builtin_amdgcn_readfirstlane(__builtin_bit_cast(int, v)));
}

// ---------------------------------------------------------------------------
// Prep: cb in FRAGMENT layout. Frag (kt, nt, kk) = 1 KB: lane (hi*16+l15)
// holds rows o=nt*16+l15, k = kt*64 + kk*32 + hi*8 .. +8 (16 B of bf16).
// Thread (o=blockIdx, i=t): kt=i>>2, sec=i&3 -> kk=sec>>1, hi0=(sec&1)*2;
// its 16 scaled-bf16 values = frag rows hi0, hi0+1 at l15=o&15, nt=o>>4.
// Also offs[o] = bias[o] + sum mu_d*scale_d*c[o,i,d].
// ---------------------------------------------------------------------------
__global__ __launch_bounds__(256) void prep_kernel(
    const float* __restrict__ omega, const float* __restrict__ phase,
    const float* __restrict__ c_basis, const float* __restrict__ bias,
    ushort* __restrict__ cb, float* __restrict__ offs)
{
  __shared__ float s_scale[DDIM];
  __shared__ float s_musc[DDIM];
  __shared__ float s_red[4];

  const int o = blockIdx.x;
  const int t = threadIdx.x;

  if (t < DDIM) {
    float w = omega[t];
    float p = phase[t];
    float mu  = expf(-0.5f * w * w) * sinf(p);
    float var = 0.5f * (1.0f - expf(-2.0f * w * w) * cosf(2.0f * p)) - mu * mu;
    float sd  = sqrtf(fmaxf(var, 0.0f));
    float sc  = 1.0f / (sd + EPSV);
    s_scale[t] = sc;
    s_musc[t]  = mu * sc;
  }
  __syncthreads();

  const float* cp = c_basis + ((size_t)o * NIN + t) * DDIM;
  float cv[DDIM];
  {
    const float4* cp4 = (const float4*)cp;
    float4 a = cp4[0], b = cp4[1], c = cp4[2], d = cp4[3];
    cv[0]=a.x; cv[1]=a.y; cv[2]=a.z; cv[3]=a.w;
    cv[4]=b.x; cv[5]=b.y; cv[6]=b.z; cv[7]=b.w;
    cv[8]=c.x; cv[9]=c.y; cv[10]=c.z; cv[11]=c.w;
    cv[12]=d.x; cv[13]=d.y; cv[14]=d.z; cv[15]=d.w;
  }

  float partial = 0.0f;
  uint pk[8];
#pragma unroll
  for (int d = 0; d < DDIM; d += 2) {
    partial += cv[d] * s_musc[d] + cv[d+1] * s_musc[d+1];
    ushort u0 = f2bf(cv[d]   * s_scale[d]);
    ushort u1 = f2bf(cv[d+1] * s_scale[d+1]);
    pk[d >> 1] = (uint)u0 | ((uint)u1 << 16);
  }

  {
    const int kt  = t >> 2;
    const int sec = t & 3;
    const int kk  = sec >> 1;
    const int hi0 = (sec & 1) * 2;
    const int nt  = o >> 4;
    const int l15 = o & 15;
    char* base = (char*)cb + (size_t)kt * 65536 + nt * 2048 + kk * 1024;
    *(uint4*)(base + (hi0 * 16 + l15) * 16)       = make_uint4(pk[0], pk[1], pk[2], pk[3]);
    *(uint4*)(base + ((hi0 + 1) * 16 + l15) * 16) = make_uint4(pk[4], pk[5], pk[6], pk[7]);
  }

#pragma unroll
  for (int off = 32; off > 0; off >>= 1) partial += __shfl_down(partial, off, 64);
  if ((t & 63) == 0) s_red[t >> 6] = partial;
  __syncthreads();
  if (t == 0) offs[o] = bias[o] + s_red[0] + s_red[1] + s_red[2] + s_red[3];
}

// ---------------------------------------------------------------------------
// GEMM: 128x512 tile, BK=64, 512 threads (8 waves: 2m x 4n, wave = 64x128).
// LDS: A0[16K] A1[16K] only (32 KB). Per iter:
//   BLOAD(bfrB, kt,kk1); x-prefetch; MFMA(kk0, bfrA); sins; BLOAD(bfrA,
//   kt+1,kk0); MFMA(kk1, bfrB); A-writes; lgkmcnt(0)+barrier (vmcnt free).
// ---------------------------------------------------------------------------
__global__ __launch_bounds__(512, 2) void gemm_kernel(
    const float* __restrict__ x, const float* __restrict__ omega,
    const float* __restrict__ phase, const ushort* __restrict__ cb,
    const float* __restrict__ offs, float* __restrict__ out)
{
  extern __shared__ char lds[];   // 2 x 16 KB A buffers

  const int t    = threadIdx.x;
  const int lane = t & 63;
  const int wid  = t >> 6;
  const int wm   = wid >> 2;       // 0..1
  const int wn   = wid & 3;        // 0..3
  const int row0 = blockIdx.x * BM;

  // uniform omega/phase in SGPRs (readfirstlane) -> zero VGPR cost
  float wv[DDIM], pv[DDIM];
#pragma unroll
  for (int d = 0; d < DDIM; ++d) {
    wv[d] = sgpr_f(omega[d] * INV2PI);
    pv[d] = sgpr_f(phase[d] * INV2PI);
  }

  f32x4 acc[4][8];
#pragma unroll
  for (int m = 0; m < 4; ++m)
#pragma unroll
    for (int n = 0; n < 8; ++n) acc[m][n] = (f32x4){0.f, 0.f, 0.f, 0.f};

  // A staging: thread t -> row t>>2 (0..127), i-slot t&3; 1 x -> 16 sins
  const int arow = t >> 2;
  const int acol = t & 3;
  const float* xbase = x + (size_t)(row0 + arow) * NIN + acol;
  const int aswz = (arow & 7) << 4;
  const int ab0  = arow * 128 + acol * 32;

  const int hi  = lane >> 4;       // 0..3
  const int l15 = lane & 15;

  // per-wave B-fragment base: frag(kt, nt=wn*8+n, kk) at
  // cb + kt*65536 + nt*2048 + kk*1024 + lane*16  (1 KB, wave-coalesced)
  const char* cbW = (const char*)cb + (wn * 8) * 2048 + lane * 16;

#define BLOAD(dst_, kt_, kk_)                                                  \
    _Pragma("unroll")                                                          \
    for (int n = 0; n < 8; ++n)                                                \
      dst_[n] = *(const bf16x8*)(cbW + (size_t)(kt_) * 65536                   \
                                  + n * 2048 + (kk_) * 1024);

  // 16 sins -> 8 packed bf16-pair words in pk[] (pure VALU/trans, no stores)
#define SINS_ALL(xx_)                                                          \
    _Pragma("unroll")                                                          \
    for (int d = 0; d < DDIM; d += 2) {                                        \
      float s0 = __builtin_amdgcn_sinf(fmaf(wv[d],   (xx_), pv[d]));           \
      float s1 = __builtin_amdgcn_sinf(fmaf(wv[d+1], (xx_), pv[d+1]));         \
      uint u0 = __builtin_bit_cast(uint, s0) + 0x8000u;                        \
      uint u1 = __builtin_bit_cast(uint, s1) + 0x8000u;                        \
      pk[d >> 1] = __builtin_amdgcn_perm(u1, u0, 0x07060302u);                 \
    }

  // two swizzled ds_write_b128 of the packed sins into A buffer sb_
#define A_WRITE2(sb_)                                                          \
    *(uint4*)(lds + (sb_) * ABYTES + ((ab0     ) ^ aswz)) =                    \
        make_uint4(pk[0], pk[1], pk[2], pk[3]);                                \
    *(uint4*)(lds + (sb_) * ABYTES + ((ab0 + 16) ^ aswz)) =                    \
        make_uint4(pk[4], pk[5], pk[6], pk[7]);

  // A-frags from LDS buf mb_, kk_ half; 32 MFMAs against bfr_ (registers)
#define MFMA_HALF(mb_, kk_, bfr_)                                              \
  {                                                                            \
    const char* AsB = lds + (mb_) * ABYTES;                                    \
    bf16x8 af[4];                                                              \
    _Pragma("unroll")                                                          \
    for (int m = 0; m < 4; ++m) {                                              \
      int rr = wm * 64 + m * 16 + l15;                                         \
      af[m] = *(const bf16x8*)(AsB + ((rr*128 + (kk_)*64 + hi*16) ^ ((rr&7)<<4))); \
    }                                                                          \
    __builtin_amdgcn_s_setprio(1);                                             \
    _Pragma("unroll")                                                          \
    for (int m = 0; m < 4; ++m)                                                \
      _Pragma("unroll")                                                        \
      for (int n = 0; n < 8; ++n)                                              \
        acc[m][n] = __builtin_amdgcn_mfma_f32_16x16x32_bf16(af[m], bfr_[n], acc[m][n], 0, 0, 0); \
    __builtin_amdgcn_s_setprio(0);                                             \
  }

  // One iter: invariant on entry = bfrA holds frags(kt, kk0), A(kt) in buf mb_.
  // On exit = bfrA holds frags(kt+1, kk0) (possibly in flight across barrier).
#define BODY(kt_, mb_, sb_, XU_, XL_)                                          \
  {                                                                            \
    BLOAD(bfrB, kt_, 1)                                                        \
    XL_ = xbase[((kt_) + 2 < NKT ? (kt_) + 2 : NKT - 1) * 4];                  \
    MFMA_HALF(mb_, 0, bfrA)                                                    \
    uint pk[8];                                                                \
    SINS_ALL(XU_)                                                              \
    BLOAD(bfrA, ((kt_) + 1 < NKT ? (kt_) + 1 : NKT - 1), 0)                    \
    MFMA_HALF(mb_, 1, bfrB)                                                    \
    A_WRITE2(sb_)                                                              \
    __builtin_amdgcn_sched_barrier(0);                                         \
    asm volatile("s_waitcnt lgkmcnt(0)" ::: "memory");                         \
    __builtin_amdgcn_s_barrier();                                              \
    __builtin_amdgcn_sched_barrier(0);                                         \
  }

  bf16x8 bfrA[8], bfrB[8];

  // ---- prologue: x(0); bfrA <- (0,kk0); x(1); sins(x0) -> A buf0 ----
  float xs0, xs1;
  {
    float xp = xbase[0];
    BLOAD(bfrA, 0, 0)
    xs1 = xbase[4];
    uint pk[8];
    SINS_ALL(xp)
    A_WRITE2(0)
    __builtin_amdgcn_sched_barrier(0);
    asm volatile("s_waitcnt lgkmcnt(0)" ::: "memory");
    __builtin_amdgcn_s_barrier();
    __builtin_amdgcn_sched_barrier(0);
  }

  for (int kt = 0; kt < NKT; kt += 2) {
    BODY(kt,     0, 1, xs1, xs0)
    BODY(kt + 1, 1, 0, xs0, xs1)
  }

  // ---- epilogue: y = acc + offs[o] ----
#pragma unroll
  for (int n = 0; n < 8; ++n) {
    int col = wn * 128 + n * 16 + l15;
    float off = offs[col];
#pragma unroll
    for (int m = 0; m < 4; ++m) {
      int row = row0 + wm * 64 + m * 16 + hi * 4;
      float* op = out + (size_t)row * NOUT + col;
#pragma unroll
      for (int j = 0; j < 4; ++j)
        op[(size_t)j * NOUT] = acc[m][n][j] + off;
    }
  }
}

// ---------------------------------------------------------------------------
extern "C" void kernel_launch(void* const* d_in, const int* in_sizes, int n_in,
                              void* d_out, int out_size, void* d_ws, size_t ws_size,
                              hipStream_t stream) {
  const float* x       = (const float*)d_in[0];
  const float* omega   = (const float*)d_in[1];
  const float* phase   = (const float*)d_in[2];
  const float* c_basis = (const float*)d_in[3];
  const float* bias    = (const float*)d_in[4];
  float* out = (float*)d_out;

  float*  offs = (float*)d_ws;
  ushort* cb   = (ushort*)((char*)d_ws + 2048);

  prep_kernel<<<NOUT, 256, 0, stream>>>(omega, phase, c_basis, bias, cb, offs);
  gemm_kernel<<<BATCH / BM, 512, 32768, stream>>>(x, omega, phase, cb, offs, out);
}

// Round 9
// 159.542 us; speedup vs baseline: 3.0918x; 3.0918x over previous
//
#include <hip/hip_runtime.h>
#include <hip/hip_bf16.h>

// SineLayer: y[b,o] = sum_{i,d} sin(w_d*x[b,i]+p_d) * (scale_d*c[o,i,d]) + offs[o]
// GEMM: M=32768, N=512, K=4096, bf16 MFMA 16x16x32.
// R9: multi-block decorrelation. BM=64 x BN=256, 4 waves (wave=64x64, acc=64),
// LDS = 2x8K A + 2x32K B = 80 KB -> 2 independent blocks/CU whose barrier
// tails overlap each other's compute (m97-style). B LDS-read redundancy 1x.

#define BATCH 32768
#define NIN   256
#define NOUT  512
#define DDIM  16
#define BM    64
#define BN    256
#define BK    64
#define NKT   ((NIN*DDIM)/BK)     // 64 K-steps
#define TILE_BYTES (BN*BK*2)      // 32 KB per (n_blk, kt) pre-swizzled B tile
#define ABYTES (BM*BK*2)          // 8 KB per A buffer
#define BBYTES (BN*BK*2)          // 32 KB per B buffer
#define EPSV  1e-8f
#define INV2PI 0.15915494309189535f

typedef short  bf16x8 __attribute__((ext_vector_type(8)));
typedef float  f32x4  __attribute__((ext_vector_type(4)));

static __device__ __forceinline__ ushort f2bf(float f) {
  union { __hip_bfloat16 h; ushort u; } cv;
  cv.h = __float2bfloat16(f);
  return cv.u;
}

static __device__ __forceinline__ float sgpr_f(float v) {
  return __builtin_bit_cast(float,
      __builtin_amdgcn_readfirstlane(__builtin_bit_cast(int, v)));
}

// ---------------------------------------------------------------------------
// Prep: cb[o,k] = bf16(scale_d * c[o,i,d]) as pre-swizzled 256x64 tiles
// (tile idx = n_blk*NKT + kt; within tile: byte = (r*128 + kloc*2) ^ ((r&7)<<4),
// r = o&255) so a LINEAR global_load_lds copy yields the swizzled LDS image.
// offs[o] = bias[o] + sum mu_d*scale_d*c[o,i,d].
// ---------------------------------------------------------------------------
__global__ __launch_bounds__(256) void prep_kernel(
    const float* __restrict__ omega, const float* __restrict__ phase,
    const float* __restrict__ c_basis, const float* __restrict__ bias,
    ushort* __restrict__ cb, float* __restrict__ offs)
{
  __shared__ float s_scale[DDIM];
  __shared__ float s_musc[DDIM];
  __shared__ float s_red[4];

  const int o = blockIdx.x;
  const int t = threadIdx.x;

  if (t < DDIM) {
    float w = omega[t];
    float p = phase[t];
    float mu  = expf(-0.5f * w * w) * sinf(p);
    float var = 0.5f * (1.0f - expf(-2.0f * w * w) * cosf(2.0f * p)) - mu * mu;
    float sd  = sqrtf(fmaxf(var, 0.0f));
    float sc  = 1.0f / (sd + EPSV);
    s_scale[t] = sc;
    s_musc[t]  = mu * sc;
  }
  __syncthreads();

  const float* cp = c_basis + ((size_t)o * NIN + t) * DDIM;
  float cv[DDIM];
  {
    const float4* cp4 = (const float4*)cp;
    float4 a = cp4[0], b = cp4[1], c = cp4[2], d = cp4[3];
    cv[0]=a.x; cv[1]=a.y; cv[2]=a.z; cv[3]=a.w;
    cv[4]=b.x; cv[5]=b.y; cv[6]=b.z; cv[7]=b.w;
    cv[8]=c.x; cv[9]=c.y; cv[10]=c.z; cv[11]=c.w;
    cv[12]=d.x; cv[13]=d.y; cv[14]=d.z; cv[15]=d.w;
  }

  float partial = 0.0f;
  uint pk[8];
#pragma unroll
  for (int d = 0; d < DDIM; d += 2) {
    partial += cv[d] * s_musc[d] + cv[d+1] * s_musc[d+1];
    ushort u0 = f2bf(cv[d]   * s_scale[d]);
    ushort u1 = f2bf(cv[d+1] * s_scale[d+1]);
    pk[d >> 1] = (uint)u0 | ((uint)u1 << 16);
  }

  {
    const int r     = o & (BN - 1);
    const int n_blk = o >> 8;
    const int kt    = t >> 2;
    const int swz   = (r & 7) << 4;
    char* tile = (char*)cb + (size_t)(n_blk * NKT + kt) * TILE_BYTES;
    int b0 = r * 128 + (t & 3) * 32;
    *(uint4*)(tile + ((b0     ) ^ swz)) = make_uint4(pk[0], pk[1], pk[2], pk[3]);
    *(uint4*)(tile + ((b0 + 16) ^ swz)) = make_uint4(pk[4], pk[5], pk[6], pk[7]);
  }

#pragma unroll
  for (int off = 32; off > 0; off >>= 1) partial += __shfl_down(partial, off, 64);
  if ((t & 63) == 0) s_red[t >> 6] = partial;
  __syncthreads();
  if (t == 0) offs[o] = bias[o] + s_red[0] + s_red[1] + s_red[2] + s_red[3];
}

// ---------------------------------------------------------------------------
// GEMM: 64x256 tile, BK=64, 256 threads (4 waves, wave = 64 rows x 64 cols).
// LDS: A0[8K] A1[8K] B0[32K] B1[32K] = 80 KB -> 2 blocks/CU. Per iter:
//   ISSUE_B(kt+1); x-load(kt+2); sins->pk; MFMA(kt); A-writes;
//   vmcnt(1)+lgkmcnt(0) barrier.
// ---------------------------------------------------------------------------
__global__ __launch_bounds__(256, 2) void gemm_kernel(
    const float* __restrict__ x, const float* __restrict__ omega,
    const float* __restrict__ phase, const ushort* __restrict__ cb,
    const float* __restrict__ offs, float* __restrict__ out)
{
  extern __shared__ char lds[];   // A0 A1 [0,16K) ; B0 B1 [16K,80K)

  const int t    = threadIdx.x;
  const int lane = t & 63;
  const int wn   = t >> 6;         // 0..3 : wave's 64-col slice
  const int bm   = blockIdx.x >> 1;
  const int bn   = blockIdx.x & 1; // adjacent blocks share the x row-panel
  const int row0 = bm * BM;
  const int col0 = bn * BN;

  // uniform omega/phase in SGPRs (readfirstlane) -> zero VGPR cost
  float wv[DDIM], pv[DDIM];
#pragma unroll
  for (int d = 0; d < DDIM; ++d) {
    wv[d] = sgpr_f(omega[d] * INV2PI);
    pv[d] = sgpr_f(phase[d] * INV2PI);
  }

  f32x4 acc[4][4];
#pragma unroll
  for (int m = 0; m < 4; ++m)
#pragma unroll
    for (int n = 0; n < 4; ++n) acc[m][n] = (f32x4){0.f, 0.f, 0.f, 0.f};

  // A staging: thread t -> row t>>2 (0..63), i-slot t&3; 1 x -> 16 sins
  const int arow = t >> 2;
  const int acol = t & 3;
  const float* xbase = x + (size_t)(row0 + arow) * NIN + acol;
  const int aswz = (arow & 7) << 4;
  const int ab0  = arow * 128 + acol * 32;

  const int hi  = lane >> 4;       // 0..3
  const int l15 = lane & 15;

  const char* cbB = (const char*)cb + (size_t)bn * NKT * TILE_BYTES;

#define GLL(s_, d_) __builtin_amdgcn_global_load_lds(                          \
      (const __attribute__((address_space(1))) void*)(s_),                     \
      (__attribute__((address_space(3))) void*)(d_), 16, 0, 0)

  // 8 global_load_lds: 32 KB B-tile kt_ -> B buffer sb_ (compile-time sb_)
#define ISSUE_B(kt_, sb_)                                                      \
  {                                                                            \
    const char* src = cbB + (size_t)(kt_) * TILE_BYTES + wn * 8192 + lane*16;  \
    char* dst = lds + 16384 + (sb_) * BBYTES + wn * 8192;                      \
    GLL(src, dst);                 GLL(src + 1024, dst + 1024);                \
    GLL(src + 2048, dst + 2048);   GLL(src + 3072, dst + 3072);                \
    GLL(src + 4096, dst + 4096);   GLL(src + 5120, dst + 5120);                \
    GLL(src + 6144, dst + 6144);   GLL(src + 7168, dst + 7168);                \
  }

  // 16 sins -> 8 packed bf16-pair words in pk[] (pure VALU/trans, no stores)
#define SINS_ALL(xx_)                                                          \
    _Pragma("unroll")                                                          \
    for (int d = 0; d < DDIM; d += 2) {                                        \
      float s0 = __builtin_amdgcn_sinf(fmaf(wv[d],   (xx_), pv[d]));           \
      float s1 = __builtin_amdgcn_sinf(fmaf(wv[d+1], (xx_), pv[d+1]));         \
      uint u0 = __builtin_bit_cast(uint, s0) + 0x8000u;                        \
      uint u1 = __builtin_bit_cast(uint, s1) + 0x8000u;                        \
      pk[d >> 1] = __builtin_amdgcn_perm(u1, u0, 0x07060302u);                 \
    }

  // two swizzled ds_write_b128 of the packed sins into A buffer sb_
#define A_WRITE2(sb_)                                                          \
    *(uint4*)(lds + (sb_) * ABYTES + ((ab0     ) ^ aswz)) =                    \
        make_uint4(pk[0], pk[1], pk[2], pk[3]);                                \
    *(uint4*)(lds + (sb_) * ABYTES + ((ab0 + 16) ^ aswz)) =                    \
        make_uint4(pk[4], pk[5], pk[6], pk[7]);

#define MFMA_STEP(mb_)                                                         \
  {                                                                            \
    const char* AsB = lds + (mb_) * ABYTES;                                    \
    const char* BsB = lds + 16384 + (mb_) * BBYTES;                            \
    __builtin_amdgcn_s_setprio(1);                                             \
    _Pragma("unroll")                                                          \
    for (int kk = 0; kk < 2; ++kk) {                                           \
      bf16x8 af[4], bfr[4];                                                    \
      _Pragma("unroll")                                                        \
      for (int m = 0; m < 4; ++m) {                                            \
        int rr = m * 16 + l15;                                                 \
        af[m] = *(const bf16x8*)(AsB + ((rr*128 + kk*64 + hi*16) ^ ((rr&7)<<4))); \
      }                                                                        \
      _Pragma("unroll")                                                        \
      for (int n = 0; n < 4; ++n) {                                            \
        int rr = wn * 64 + n * 16 + l15;                                       \
        bfr[n] = *(const bf16x8*)(BsB + ((rr*128 + kk*64 + hi*16) ^ ((rr&7)<<4))); \
      }                                                                        \
      _Pragma("unroll")                                                        \
      for (int m = 0; m < 4; ++m)                                              \
        _Pragma("unroll")                                                      \
        for (int n = 0; n < 4; ++n)                                            \
          acc[m][n] = __builtin_amdgcn_mfma_f32_16x16x32_bf16(af[m], bfr[n], acc[m][n], 0, 0, 0); \
    }                                                                          \
    __builtin_amdgcn_s_setprio(0);                                             \
  }

#define CBAR(vm_)                                                              \
  __builtin_amdgcn_sched_barrier(0);                                           \
  asm volatile("s_waitcnt vmcnt(" #vm_ ") lgkmcnt(0)" ::: "memory");           \
  __builtin_amdgcn_s_barrier();                                                \
  __builtin_amdgcn_sched_barrier(0);

  // One iter: mfma buf mb_, stage buf sb_=mb_^1; sins for slice kt_+1 (XU_),
  // x prefetch for slice kt_+2 (XL_). No fences between sins/MFMA/A-writes.
#define BODY(kt_, mb_, sb_, XU_, XL_)                                          \
  {                                                                            \
    ISSUE_B(((kt_) + 1 < NKT ? (kt_) + 1 : NKT - 1), sb_);                     \
    __builtin_amdgcn_sched_barrier(0);                                         \
    XL_ = xbase[((kt_) + 2 < NKT ? (kt_) + 2 : NKT - 1) * 4];                  \
    __builtin_amdgcn_sched_barrier(0);                                         \
    uint pk[8];                                                                \
    SINS_ALL(XU_)                                                              \
    MFMA_STEP(mb_)                                                             \
    A_WRITE2(sb_)                                                              \
    CBAR(1)                                                                    \
  }

  // ---- prologue ----
  float xs0, xs1;
  {
    float xp = xbase[0];
    __builtin_amdgcn_sched_barrier(0);
    ISSUE_B(0, 0);
    __builtin_amdgcn_sched_barrier(0);
    xs1 = xbase[4];
    __builtin_amdgcn_sched_barrier(0);
    {
      uint pk[8];
      SINS_ALL(xp)
      A_WRITE2(0)
    }
    CBAR(1)                       // drains B(0)+x(0), keeps xs1 in flight
  }

  for (int kt = 0; kt < NKT; kt += 2) {
    BODY(kt,     0, 1, xs1, xs0)
    BODY(kt + 1, 1, 0, xs0, xs1)
  }

  // ---- epilogue: y = acc + offs[o] ----
#pragma unroll
  for (int n = 0; n < 4; ++n) {
    int col = col0 + wn * 64 + n * 16 + l15;
    float off = offs[col];
#pragma unroll
    for (int m = 0; m < 4; ++m) {
      int row = row0 + m * 16 + hi * 4;
      float* op = out + (size_t)row * NOUT + col;
#pragma unroll
      for (int j = 0; j < 4; ++j)
        op[(size_t)j * NOUT] = acc[m][n][j] + off;
    }
  }
}

// ---------------------------------------------------------------------------
extern "C" void kernel_launch(void* const* d_in, const int* in_sizes, int n_in,
                              void* d_out, int out_size, void* d_ws, size_t ws_size,
                              hipStream_t stream) {
  const float* x       = (const float*)d_in[0];
  const float* omega   = (const float*)d_in[1];
  const float* phase   = (const float*)d_in[2];
  const float* c_basis = (const float*)d_in[3];
  const float* bias    = (const float*)d_in[4];
  float* out = (float*)d_out;

  float*  offs = (float*)d_ws;
  ushort* cb   = (ushort*)((char*)d_ws + 2048);

  hipFuncSetAttribute((const void*)gemm_kernel,
                      hipFuncAttributeMaxDynamicSharedMemorySize, 81920);

  prep_kernel<<<NOUT, 256, 0, stream>>>(omega, phase, c_basis, bias, cb, offs);
  gemm_kernel<<<(BATCH / BM) * (NOUT / BN), 256, 81920, stream>>>(x, omega, phase, cb, offs, out);
}

// Round 10
// 151.560 us; speedup vs baseline: 3.2546x; 1.0527x over previous
//
#include <hip/hip_runtime.h>
#include <hip/hip_bf16.h>

// SineLayer: y[b,o] = sum_{i,d} sin(w_d*x[b,i]+p_d) * (scale_d*c[o,i,d]) + offs[o]
// GEMM: M=32768, N=512, K=4096, bf16 MFMA 16x16x32.
// R10: never-drain ring pipeline. K split into 128 slices of 32. LDS rings:
// A 4x8KB + B 4x32KB = 160KB. Per step s: gll B(s+3); sins(s+2)->cvt_pk->
// ds_write A(s+2); frag-read+32 MFMA on slice s; barrier w/ vmcnt(8)+lgkm(0).
// Staging is 3 steps ahead -> no wave ever waits on memory at the barrier.
// 64B row pitch => dense 1KB wave reads, conflict-free without swizzle.

#define BATCH 32768
#define NIN   256
#define NOUT  512
#define DDIM  16
#define BM    128
#define BN    512
#define NKS   128              // K-slices of 32 (K = 4096)
#define ASLICE 8192            // BM*32*2 bytes
#define BSLICE 32768           // BN*32*2 bytes
#define EPSV  1e-8f
#define INV2PI 0.15915494309189535f

typedef short  bf16x8 __attribute__((ext_vector_type(8)));
typedef float  f32x4  __attribute__((ext_vector_type(4)));

static __device__ __forceinline__ ushort f2bf(float f) {
  union { __hip_bfloat16 h; ushort u; } cv;
  cv.h = __float2bfloat16(f);
  return cv.u;
}

static __device__ __forceinline__ uint cvt_pk(float lo, float hi) {
  uint r;
  asm("v_cvt_pk_bf16_f32 %0, %1, %2" : "=v"(r) : "v"(lo), "v"(hi));
  return r;
}

// ---------------------------------------------------------------------------
// Prep: cb linear slice layout. Slice ks (k = ks*32..+32) = 32KB: row o (512)
// at o*64, byte within row = (k%32)*2. Thread (o=blockIdx, i=t): ks = i>>1,
// bytes (i&1)*32 + {0,16}. offs[o] = bias[o] + sum mu_d*scale_d*c[o,i,d].
// ---------------------------------------------------------------------------
__global__ __launch_bounds__(256) void prep_kernel(
    const float* __restrict__ omega, const float* __restrict__ phase,
    const float* __restrict__ c_basis, const float* __restrict__ bias,
    ushort* __restrict__ cb, float* __restrict__ offs)
{
  __shared__ float s_scale[DDIM];
  __shared__ float s_musc[DDIM];
  __shared__ float s_red[4];

  const int o = blockIdx.x;
  const int t = threadIdx.x;

  if (t < DDIM) {
    float w = omega[t];
    float p = phase[t];
    float mu  = expf(-0.5f * w * w) * sinf(p);
    float var = 0.5f * (1.0f - expf(-2.0f * w * w) * cosf(2.0f * p)) - mu * mu;
    float sd  = sqrtf(fmaxf(var, 0.0f));
    float sc  = 1.0f / (sd + EPSV);
    s_scale[t] = sc;
    s_musc[t]  = mu * sc;
  }
  __syncthreads();

  const float* cp = c_basis + ((size_t)o * NIN + t) * DDIM;
  float cv[DDIM];
  {
    const float4* cp4 = (const float4*)cp;
    float4 a = cp4[0], b = cp4[1], c = cp4[2], d = cp4[3];
    cv[0]=a.x; cv[1]=a.y; cv[2]=a.z; cv[3]=a.w;
    cv[4]=b.x; cv[5]=b.y; cv[6]=b.z; cv[7]=b.w;
    cv[8]=c.x; cv[9]=c.y; cv[10]=c.z; cv[11]=c.w;
    cv[12]=d.x; cv[13]=d.y; cv[14]=d.z; cv[15]=d.w;
  }

  float partial = 0.0f;
  uint pk[8];
#pragma unroll
  for (int d = 0; d < DDIM; d += 2) {
    partial += cv[d] * s_musc[d] + cv[d+1] * s_musc[d+1];
    ushort u0 = f2bf(cv[d]   * s_scale[d]);
    ushort u1 = f2bf(cv[d+1] * s_scale[d+1]);
    pk[d >> 1] = (uint)u0 | ((uint)u1 << 16);
  }

  {
    const int ks = t >> 1;
    char* dst = (char*)cb + (size_t)ks * BSLICE + o * 64 + (t & 1) * 32;
    *(uint4*)(dst)      = make_uint4(pk[0], pk[1], pk[2], pk[3]);
    *(uint4*)(dst + 16) = make_uint4(pk[4], pk[5], pk[6], pk[7]);
  }

#pragma unroll
  for (int off = 32; off > 0; off >>= 1) partial += __shfl_down(partial, off, 64);
  if ((t & 63) == 0) s_red[t >> 6] = partial;
  __syncthreads();
  if (t == 0) offs[o] = bias[o] + s_red[0] + s_red[1] + s_red[2] + s_red[3];
}

// ---------------------------------------------------------------------------
// GEMM: 128x512 tile, 512 threads (8 waves: 2m x 4n, wave = 64x128).
// LDS: A ring [0,32K) 4 slots x 8KB; B ring [32K,160K) 4 slots x 32KB.
// ---------------------------------------------------------------------------
__global__ __launch_bounds__(512, 2) void gemm_kernel(
    const float* __restrict__ x, const float* __restrict__ omega,
    const float* __restrict__ phase, const ushort* __restrict__ cb,
    const float* __restrict__ offs, float* __restrict__ out)
{
  extern __shared__ char lds[];

  const int t    = threadIdx.x;
  const int lane = t & 63;
  const int wid  = t >> 6;
  const int wm   = wid >> 2;       // 0..1
  const int wn   = wid & 3;        // 0..3
  const int row0 = blockIdx.x * BM;

  f32x4 acc[4][8];
#pragma unroll
  for (int m = 0; m < 4; ++m)
#pragma unroll
    for (int n = 0; n < 8; ++n) acc[m][n] = (f32x4){0.f, 0.f, 0.f, 0.f};

  // A staging: thread t -> row r = t>>2; sub = t&3 -> (i_local, d-half).
  // Per step: 8 sins (d = d0..d0+7) for x[row, 2*ks + il] -> one uint4 write.
  const int r   = t >> 2;          // 0..127
  const int sub = t & 3;
  const int il  = sub >> 1;        // i_local 0..1
  const int d0  = (sub & 1) * 8;   // d-half
  const float* xbase = x + (size_t)(row0 + r) * NIN + il;
  const int awa = r * 64 + il * 32 + (sub & 1) * 16;  // byte offset in A slice

  // this thread's 8 omega/phase values (d0..d0+7), revolutions folded in
  float wvt[8], pvt[8];
#pragma unroll
  for (int j = 0; j < 8; ++j) {
    wvt[j] = omega[d0 + j] * INV2PI;
    pvt[j] = phase[d0 + j] * INV2PI;
  }

  const int hi  = lane >> 4;       // 0..3
  const int l15 = lane & 15;

#define GLL(s_, d_) __builtin_amdgcn_global_load_lds(                          \
      (const __attribute__((address_space(1))) void*)(s_),                     \
      (__attribute__((address_space(3))) void*)(d_), 16, 0, 0)

  // 4 gll: 32KB B slice ks_ -> ring slot slot_ (compile-time slot_)
#define ISSUE_B(ks_, slot_)                                                    \
  {                                                                            \
    const char* src = (const char*)cb + (size_t)(ks_) * BSLICE                 \
                      + wid * 1024 + lane * 16;                                \
    char* dst = lds + 32768 + (slot_) * BSLICE + wid * 1024;                   \
    GLL(src, dst);             GLL(src + 8192,  dst + 8192);                   \
    GLL(src + 16384, dst + 16384); GLL(src + 24576, dst + 24576);              \
  }

  // 8 sins -> 4 packed bf16-pair words via v_cvt_pk_bf16_f32
#define SINS4(xx_)                                                             \
    _Pragma("unroll")                                                          \
    for (int j = 0; j < 8; j += 2) {                                           \
      float s0 = __builtin_amdgcn_sinf(fmaf(wvt[j],     (xx_), pvt[j]));       \
      float s1 = __builtin_amdgcn_sinf(fmaf(wvt[j + 1], (xx_), pvt[j + 1]));   \
      pk[j >> 1] = cvt_pk(s0, s1);                                             \
    }

#define AWRITE(slot_)                                                          \
    *(uint4*)(lds + (slot_) * ASLICE + awa) = make_uint4(pk[0],pk[1],pk[2],pk[3]);

  // fragment reads (dense 1KB per wave-read, conflict-free) + 32 MFMA
#define FRAG_MFMA(slot_)                                                       \
  {                                                                            \
    const char* AsB = lds + (slot_) * ASLICE;                                  \
    const char* BsB = lds + 32768 + (slot_) * BSLICE;                          \
    bf16x8 af[4];                                                              \
    _Pragma("unroll")                                                          \
    for (int m = 0; m < 4; ++m)                                                \
      af[m] = *(const bf16x8*)(AsB + (wm*64 + m*16 + l15) * 64 + hi * 16);     \
    bf16x8 bfr[8];                                                             \
    _Pragma("unroll")                                                          \
    for (int n = 0; n < 8; ++n)                                                \
      bfr[n] = *(const bf16x8*)(BsB + (wn*128 + n*16 + l15) * 64 + hi * 16);   \
    __builtin_amdgcn_s_setprio(1);                                             \
    _Pragma("unroll")                                                          \
    for (int m = 0; m < 4; ++m)                                                \
      _Pragma("unroll")                                                        \
      for (int n = 0; n < 8; ++n)                                              \
        acc[m][n] = __builtin_amdgcn_mfma_f32_16x16x32_bf16(af[m], bfr[n], acc[m][n], 0, 0, 0); \
    __builtin_amdgcn_s_setprio(0);                                             \
  }

  // One step s: read slot rd_=s&3; A-write slot aw_=(s+2)&3 (sins slice s+2,
  // x = XU_); gll slot bg_=(s+3)&3 (slice s+3); prefetch XL_ = x(slice s+3).
  // Barrier: vmcnt(8) keeps this+prev step's glls in flight, drains slice
  // s+1's (issued 2 steps ago). lgkmcnt(0) drains A-write + frag reads.
#define BODY(s_, rd_, aw_, bg_, XU_, XL_)                                      \
  {                                                                            \
    ISSUE_B(((s_) + 3 < NKS ? (s_) + 3 : NKS - 1), bg_);                       \
    XL_ = xbase[((s_) + 3 < NKS ? (s_) + 3 : NKS - 1) * 2];                    \
    __builtin_amdgcn_sched_barrier(0);                                         \
    uint pk[4];                                                                \
    SINS4(XU_)                                                                 \
    AWRITE(aw_)                                                                \
    FRAG_MFMA(rd_)                                                             \
    __builtin_amdgcn_sched_barrier(0);                                         \
    asm volatile("s_waitcnt vmcnt(8) lgkmcnt(0)" ::: "memory");                \
    __builtin_amdgcn_s_barrier();                                              \
    __builtin_amdgcn_sched_barrier(0);                                         \
  }

  // ---- prologue: stage B(0..2), A(0..1); x for slice 2; full drain ----
  float xsA, xsB;
  {
    float xp0 = xbase[0];            // slice 0
    float xp1 = xbase[2];            // slice 1
    ISSUE_B(0, 0) ISSUE_B(1, 1) ISSUE_B(2, 2)
    xsA = xbase[4];                  // slice 2 (used at s=0)
    uint pk[4];
    SINS4(xp0) AWRITE(0)
    SINS4(xp1) AWRITE(1)
    __builtin_amdgcn_sched_barrier(0);
    asm volatile("s_waitcnt vmcnt(0) lgkmcnt(0)" ::: "memory");
    __builtin_amdgcn_s_barrier();
    __builtin_amdgcn_sched_barrier(0);
  }

  for (int s = 0; s < NKS; s += 4) {
    BODY(s,     0, 2, 3, xsA, xsB)
    BODY(s + 1, 1, 3, 0, xsB, xsA)
    BODY(s + 2, 2, 0, 1, xsA, xsB)
    BODY(s + 3, 3, 1, 2, xsB, xsA)
  }

  // ---- epilogue: y = acc + offs[o] ----
#pragma unroll
  for (int n = 0; n < 8; ++n) {
    int col = wn * 128 + n * 16 + l15;
    float off = offs[col];
#pragma unroll
    for (int m = 0; m < 4; ++m) {
      int row = row0 + wm * 64 + m * 16 + hi * 4;
      float* op = out + (size_t)row * NOUT + col;
#pragma unroll
      for (int j = 0; j < 4; ++j)
        op[(size_t)j * NOUT] = acc[m][n][j] + off;
    }
  }
}

// ---------------------------------------------------------------------------
extern "C" void kernel_launch(void* const* d_in, const int* in_sizes, int n_in,
                              void* d_out, int out_size, void* d_ws, size_t ws_size,
                              hipStream_t stream) {
  const float* x       = (const float*)d_in[0];
  const float* omega   = (const float*)d_in[1];
  const float* phase   = (const float*)d_in[2];
  const float* c_basis = (const float*)d_in[3];
  const float* bias    = (const float*)d_in[4];
  float* out = (float*)d_out;

  float*  offs = (float*)d_ws;
  ushort* cb   = (ushort*)((char*)d_ws + 2048);

  hipFuncSetAttribute((const void*)gemm_kernel,
                      hipFuncAttributeMaxDynamicSharedMemorySize, 163840);

  prep_kernel<<<NOUT, 256, 0, stream>>>(omega, phase, c_basis, bias, cb, offs);
  gemm_kernel<<<BATCH / BM, 512, 163840, stream>>>(x, omega, phase, cb, offs, out);
}

// Round 11
// 151.060 us; speedup vs baseline: 3.2654x; 1.0033x over previous
//
#include <hip/hip_runtime.h>
#include <hip/hip_bf16.h>

// SineLayer: y[b,o] = sum_{i,d} sin(w_d*x[b,i]+p_d) * (scale_d*c[o,i,d]) + offs[o]
// GEMM: M=32768, N=512, K=4096, bf16 MFMA 16x16x32.
// R11: R10 never-drain ring + unit-swizzle to kill the 8-way bank conflict.
// Layout: unit h (16B) of row r stored at r*64 + (h ^ ((r>>1)&3))*16.
// Fragment-read unit index hu = hi ^ ((l15>>1)&3) is a per-thread constant.

#define BATCH 32768
#define NIN   256
#define NOUT  512
#define DDIM  16
#define BM    128
#define BN    512
#define NKS   128              // K-slices of 32 (K = 4096)
#define ASLICE 8192            // BM*32*2 bytes
#define BSLICE 32768           // BN*32*2 bytes
#define EPSV  1e-8f
#define INV2PI 0.15915494309189535f

typedef short  bf16x8 __attribute__((ext_vector_type(8)));
typedef float  f32x4  __attribute__((ext_vector_type(4)));

static __device__ __forceinline__ ushort f2bf(float f) {
  union { __hip_bfloat16 h; ushort u; } cv;
  cv.h = __float2bfloat16(f);
  return cv.u;
}

static __device__ __forceinline__ uint cvt_pk(float lo, float hi) {
  uint r;
  asm("v_cvt_pk_bf16_f32 %0, %1, %2" : "=v"(r) : "v"(lo), "v"(hi));
  return r;
}

// ---------------------------------------------------------------------------
// Prep: cb slice layout with unit-swizzle. Slice ks (k = ks*32..+32) = 32KB:
// row o at o*64; unit h (k-portion h*8..+8) at (h ^ ((o>>1)&3))*16 within row.
// Linear gll copy (LDS byte = global byte) then yields the swizzled image.
// offs[o] = bias[o] + sum mu_d*scale_d*c[o,i,d].
// ---------------------------------------------------------------------------
__global__ __launch_bounds__(256) void prep_kernel(
    const float* __restrict__ omega, const float* __restrict__ phase,
    const float* __restrict__ c_basis, const float* __restrict__ bias,
    ushort* __restrict__ cb, float* __restrict__ offs)
{
  __shared__ float s_scale[DDIM];
  __shared__ float s_musc[DDIM];
  __shared__ float s_red[4];

  const int o = blockIdx.x;
  const int t = threadIdx.x;

  if (t < DDIM) {
    float w = omega[t];
    float p = phase[t];
    float mu  = expf(-0.5f * w * w) * sinf(p);
    float var = 0.5f * (1.0f - expf(-2.0f * w * w) * cosf(2.0f * p)) - mu * mu;
    float sd  = sqrtf(fmaxf(var, 0.0f));
    float sc  = 1.0f / (sd + EPSV);
    s_scale[t] = sc;
    s_musc[t]  = mu * sc;
  }
  __syncthreads();

  const float* cp = c_basis + ((size_t)o * NIN + t) * DDIM;
  float cv[DDIM];
  {
    const float4* cp4 = (const float4*)cp;
    float4 a = cp4[0], b = cp4[1], c = cp4[2], d = cp4[3];
    cv[0]=a.x; cv[1]=a.y; cv[2]=a.z; cv[3]=a.w;
    cv[4]=b.x; cv[5]=b.y; cv[6]=b.z; cv[7]=b.w;
    cv[8]=c.x; cv[9]=c.y; cv[10]=c.z; cv[11]=c.w;
    cv[12]=d.x; cv[13]=d.y; cv[14]=d.z; cv[15]=d.w;
  }

  float partial = 0.0f;
  uint pk[8];
#pragma unroll
  for (int d = 0; d < DDIM; d += 2) {
    partial += cv[d] * s_musc[d] + cv[d+1] * s_musc[d+1];
    ushort u0 = f2bf(cv[d]   * s_scale[d]);
    ushort u1 = f2bf(cv[d+1] * s_scale[d+1]);
    pk[d >> 1] = (uint)u0 | ((uint)u1 << 16);
  }

  {
    const int ks = t >> 1;
    const int h0 = (t & 1) * 2;          // units h0, h0+1
    const int fo = (o >> 1) & 3;
    char* rowp = (char*)cb + (size_t)ks * BSLICE + o * 64;
    *(uint4*)(rowp + ((h0    ) ^ fo) * 16) = make_uint4(pk[0], pk[1], pk[2], pk[3]);
    *(uint4*)(rowp + ((h0 + 1) ^ fo) * 16) = make_uint4(pk[4], pk[5], pk[6], pk[7]);
  }

#pragma unroll
  for (int off = 32; off > 0; off >>= 1) partial += __shfl_down(partial, off, 64);
  if ((t & 63) == 0) s_red[t >> 6] = partial;
  __syncthreads();
  if (t == 0) offs[o] = bias[o] + s_red[0] + s_red[1] + s_red[2] + s_red[3];
}

// ---------------------------------------------------------------------------
// GEMM: 128x512 tile, 512 threads (8 waves: 2m x 4n, wave = 64x128).
// LDS: A ring [0,32K) 4 slots x 8KB; B ring [32K,160K) 4 slots x 32KB.
// Per step s: gll B(s+3); sins(s+2)->cvt_pk->ds_write A(s+2); frag-read +
// 32 MFMA slice s; barrier w/ vmcnt(8)+lgkmcnt(0) (never-drain).
// ---------------------------------------------------------------------------
__global__ __launch_bounds__(512, 2) void gemm_kernel(
    const float* __restrict__ x, const float* __restrict__ omega,
    const float* __restrict__ phase, const ushort* __restrict__ cb,
    const float* __restrict__ offs, float* __restrict__ out)
{
  extern __shared__ char lds[];

  const int t    = threadIdx.x;
  const int lane = t & 63;
  const int wid  = t >> 6;
  const int wm   = wid >> 2;       // 0..1
  const int wn   = wid & 3;        // 0..3
  const int row0 = blockIdx.x * BM;

  f32x4 acc[4][8];
#pragma unroll
  for (int m = 0; m < 4; ++m)
#pragma unroll
    for (int n = 0; n < 8; ++n) acc[m][n] = (f32x4){0.f, 0.f, 0.f, 0.f};

  // A staging: thread t -> row r = t>>2; sub = t&3 = unit h; 8 sins/step.
  const int r   = t >> 2;          // 0..127
  const int sub = t & 3;
  const int il  = sub >> 1;        // i_local 0..1
  const int d0  = (sub & 1) * 8;   // d-half
  const float* xbase = x + (size_t)(row0 + r) * NIN + il;
  // swizzled A-write offset: r*64 + (sub ^ ((r>>1)&3))*16  (per-thread const)
  const int awa = r * 64 + ((sub ^ ((r >> 1) & 3)) * 16);

  // this thread's 8 omega/phase values (d0..d0+7), revolutions folded in
  float wvt[8], pvt[8];
#pragma unroll
  for (int j = 0; j < 8; ++j) {
    wvt[j] = omega[d0 + j] * INV2PI;
    pvt[j] = phase[d0 + j] * INV2PI;
  }

  const int hi  = lane >> 4;       // 0..3
  const int l15 = lane & 15;
  const int hu  = (hi ^ ((l15 >> 1) & 3)) * 16;  // swizzled unit byte offset

#define GLL(s_, d_) __builtin_amdgcn_global_load_lds(                          \
      (const __attribute__((address_space(1))) void*)(s_),                     \
      (__attribute__((address_space(3))) void*)(d_), 16, 0, 0)

  // 4 gll: 32KB B slice ks_ -> ring slot slot_ (compile-time slot_)
#define ISSUE_B(ks_, slot_)                                                    \
  {                                                                            \
    const char* src = (const char*)cb + (size_t)(ks_) * BSLICE                 \
                      + wid * 1024 + lane * 16;                                \
    char* dst = lds + 32768 + (slot_) * BSLICE + wid * 1024;                   \
    GLL(src, dst);             GLL(src + 8192,  dst + 8192);                   \
    GLL(src + 16384, dst + 16384); GLL(src + 24576, dst + 24576);              \
  }

  // 8 sins -> 4 packed bf16-pair words via v_cvt_pk_bf16_f32
#define SINS4(xx_)                                                             \
    _Pragma("unroll")                                                          \
    for (int j = 0; j < 8; j += 2) {                                           \
      float s0 = __builtin_amdgcn_sinf(fmaf(wvt[j],     (xx_), pvt[j]));       \
      float s1 = __builtin_amdgcn_sinf(fmaf(wvt[j + 1], (xx_), pvt[j + 1]));   \
      pk[j >> 1] = cvt_pk(s0, s1);                                             \
    }

#define AWRITE(slot_)                                                          \
    *(uint4*)(lds + (slot_) * ASLICE + awa) = make_uint4(pk[0],pk[1],pk[2],pk[3]);

  // fragment reads (unit-swizzled, 2-way max = free) + 32 MFMA
#define FRAG_MFMA(slot_)                                                       \
  {                                                                            \
    const char* AsB = lds + (slot_) * ASLICE;                                  \
    const char* BsB = lds + 32768 + (slot_) * BSLICE;                          \
    bf16x8 af[4];                                                              \
    _Pragma("unroll")                                                          \
    for (int m = 0; m < 4; ++m)                                                \
      af[m] = *(const bf16x8*)(AsB + (wm*64 + m*16 + l15) * 64 + hu);          \
    bf16x8 bfr[8];                                                             \
    _Pragma("unroll")                                                          \
    for (int n = 0; n < 8; ++n)                                                \
      bfr[n] = *(const bf16x8*)(BsB + (wn*128 + n*16 + l15) * 64 + hu);        \
    __builtin_amdgcn_s_setprio(1);                                             \
    _Pragma("unroll")                                                          \
    for (int m = 0; m < 4; ++m)                                                \
      _Pragma("unroll")                                                        \
      for (int n = 0; n < 8; ++n)                                              \
        acc[m][n] = __builtin_amdgcn_mfma_f32_16x16x32_bf16(af[m], bfr[n], acc[m][n], 0, 0, 0); \
    __builtin_amdgcn_s_setprio(0);                                             \
  }

  // One step s: read slot rd_=s&3; A-write slot aw_=(s+2)&3 (sins slice s+2,
  // x = XU_); gll slot bg_=(s+3)&3 (slice s+3); prefetch XL_ = x(slice s+3).
  // Barrier: vmcnt(8) drains slice s+1's glls (issued 2 steps ago), keeps
  // the newest 8 vm ops in flight. lgkmcnt(0) drains A-write + frag reads.
#define BODY(s_, rd_, aw_, bg_, XU_, XL_)                                      \
  {                                                                            \
    ISSUE_B(((s_) + 3 < NKS ? (s_) + 3 : NKS - 1), bg_);                       \
    XL_ = xbase[((s_) + 3 < NKS ? (s_) + 3 : NKS - 1) * 2];                    \
    __builtin_amdgcn_sched_barrier(0);                                         \
    uint pk[4];                                                                \
    SINS4(XU_)                                                                 \
    AWRITE(aw_)                                                                \
    FRAG_MFMA(rd_)                                                             \
    __builtin_amdgcn_sched_barrier(0);                                         \
    asm volatile("s_waitcnt vmcnt(8) lgkmcnt(0)" ::: "memory");                \
    __builtin_amdgcn_s_barrier();                                              \
    __builtin_amdgcn_sched_barrier(0);                                         \
  }

  // ---- prologue: stage B(0..2), A(0..1); x for slice 2; full drain ----
  float xsA, xsB;
  {
    float xp0 = xbase[0];            // slice 0
    float xp1 = xbase[2];            // slice 1
    ISSUE_B(0, 0) ISSUE_B(1, 1) ISSUE_B(2, 2)
    xsA = xbase[4];                  // slice 2 (used at s=0)
    uint pk[4];
    SINS4(xp0) AWRITE(0)
    SINS4(xp1) AWRITE(1)
    __builtin_amdgcn_sched_barrier(0);
    asm volatile("s_waitcnt vmcnt(0) lgkmcnt(0)" ::: "memory");
    __builtin_amdgcn_s_barrier();
    __builtin_amdgcn_sched_barrier(0);
  }

  for (int s = 0; s < NKS; s += 4) {
    BODY(s,     0, 2, 3, xsA, xsB)
    BODY(s + 1, 1, 3, 0, xsB, xsA)
    BODY(s + 2, 2, 0, 1, xsA, xsB)
    BODY(s + 3, 3, 1, 2, xsB, xsA)
  }

  // ---- epilogue: y = acc + offs[o] ----
#pragma unroll
  for (int n = 0; n < 8; ++n) {
    int col = wn * 128 + n * 16 + l15;
    float off = offs[col];
#pragma unroll
    for (int m = 0; m < 4; ++m) {
      int row = row0 + wm * 64 + m * 16 + hi * 4;
      float* op = out + (size_t)row * NOUT + col;
#pragma unroll
      for (int j = 0; j < 4; ++j)
        op[(size_t)j * NOUT] = acc[m][n][j] + off;
    }
  }
}

// ---------------------------------------------------------------------------
extern "C" void kernel_launch(void* const* d_in, const int* in_sizes, int n_in,
                              void* d_out, int out_size, void* d_ws, size_t ws_size,
                              hipStream_t stream) {
  const float* x       = (const float*)d_in[0];
  const float* omega   = (const float*)d_in[1];
  const float* phase   = (const float*)d_in[2];
  const float* c_basis = (const float*)d_in[3];
  const float* bias    = (const float*)d_in[4];
  float* out = (float*)d_out;

  float*  offs = (float*)d_ws;
  ushort* cb   = (ushort*)((char*)d_ws + 2048);

  hipFuncSetAttribute((const void*)gemm_kernel,
                      hipFuncAttributeMaxDynamicSharedMemorySize, 163840);

  prep_kernel<<<NOUT, 256, 0, stream>>>(omega, phase, c_basis, bias, cb, offs);
  gemm_kernel<<<BATCH / BM, 512, 163840, stream>>>(x, omega, phase, cb, offs, out);
}